// Round 1
// baseline (500.240 us; speedup 1.0000x reference)
//
#include <hip/hip_runtime.h>

// ExpFlow: scaling-and-squaring exponentiation of a velocity field.
// x: [N=2, C=3, D=128, H=128, W=128] f32. u0 = x/32; 5x: u <- u + warp(u, id+u).
// Layout kept [N,3,D,H,W] (SoA) end-to-end; ping-pong d_ws <-> d_out so the
// 5th step lands in d_out.

namespace {
constexpr int kD = 128, kH = 128, kW = 128, kN = 2, kC = 3;
constexpr int kPlane = kD * kH * kW;        // 2^21
constexpr int kVol   = kC * kPlane;         // per-batch elements
constexpr int kTotalVox   = kN * kPlane;    // step-kernel threads
constexpr int kTotalElems = kN * kVol;      // 12,582,912
constexpr float kScale0 = 1.0f / 32.0f;     // SCALE / 2^STEPS
}

__global__ __launch_bounds__(256) void scale_kernel(const float* __restrict__ x,
                                                    float* __restrict__ u) {
    int i = blockIdx.x * 256 + threadIdx.x;
    u[i] = x[i] * kScale0;
}

__global__ __launch_bounds__(256) void step_kernel(const float* __restrict__ u,
                                                   float* __restrict__ out) {
    int idx = blockIdx.x * 256 + threadIdx.x;   // < kTotalVox
    int n = idx >> 21;                          // kPlane = 2^21
    int r = idx & (kPlane - 1);
    int w = r & 127;
    int h = (r >> 7) & 127;
    int d = r >> 14;

    const float* __restrict__ ub = u + n * kVol;
    float uc[3];
    uc[0] = ub[r];                 // ux
    uc[1] = ub[kPlane + r];        // uy
    uc[2] = ub[2 * kPlane + r];    // uz

    // Sample position in voxel coords (align_corners=True), border clamp.
    float px = fminf(fmaxf((float)w + uc[0] * 63.5f, 0.0f), 127.0f);
    float py = fminf(fmaxf((float)h + uc[1] * 63.5f, 0.0f), 127.0f);
    float pz = fminf(fmaxf((float)d + uc[2] * 63.5f, 0.0f), 127.0f);

    float x0f = floorf(px), y0f = floorf(py), z0f = floorf(pz);
    float wx = px - x0f, wy = py - y0f, wz = pz - z0f;
    float omx = 1.0f - wx, omy = 1.0f - wy, omz = 1.0f - wz;
    int x0 = (int)x0f, y0 = (int)y0f, z0 = (int)z0f;
    int x1 = min(x0 + 1, kW - 1);
    int y1 = min(y0 + 1, kH - 1);
    int z1 = min(z0 + 1, kD - 1);

    int o000 = (z0 << 14) + (y0 << 7) + x0;
    int o001 = (z0 << 14) + (y0 << 7) + x1;
    int o010 = (z0 << 14) + (y1 << 7) + x0;
    int o011 = (z0 << 14) + (y1 << 7) + x1;
    int o100 = (z1 << 14) + (y0 << 7) + x0;
    int o101 = (z1 << 14) + (y0 << 7) + x1;
    int o110 = (z1 << 14) + (y1 << 7) + x0;
    int o111 = (z1 << 14) + (y1 << 7) + x1;

    float* __restrict__ ob = out + n * kVol;
    #pragma unroll
    for (int c = 0; c < 3; ++c) {
        const float* __restrict__ up = ub + c * kPlane;
        float v000 = up[o000], v001 = up[o001];
        float v010 = up[o010], v011 = up[o011];
        float v100 = up[o100], v101 = up[o101];
        float v110 = up[o110], v111 = up[o111];
        // match reference lerp ordering: x, then y, then z
        float c00 = v000 * omx + v001 * wx;
        float c01 = v010 * omx + v011 * wx;
        float c10 = v100 * omx + v101 * wx;
        float c11 = v110 * omx + v111 * wx;
        float c0 = c00 * omy + c01 * wy;
        float c1 = c10 * omy + c11 * wy;
        float s  = c0 * omz + c1 * wz;
        ob[c * kPlane + r] = uc[c] + s;
    }
}

extern "C" void kernel_launch(void* const* d_in, const int* in_sizes, int n_in,
                              void* d_out, int out_size, void* d_ws, size_t ws_size,
                              hipStream_t stream) {
    const float* x = (const float*)d_in[0];
    float* out = (float*)d_out;
    float* ws  = (float*)d_ws;   // ping buffer, kTotalElems floats (50.3 MB)

    scale_kernel<<<kTotalElems / 256, 256, 0, stream>>>(x, ws);

    const int grd = kTotalVox / 256;
    step_kernel<<<grd, 256, 0, stream>>>(ws, out);   // step 1
    step_kernel<<<grd, 256, 0, stream>>>(out, ws);   // step 2
    step_kernel<<<grd, 256, 0, stream>>>(ws, out);   // step 3
    step_kernel<<<grd, 256, 0, stream>>>(out, ws);   // step 4
    step_kernel<<<grd, 256, 0, stream>>>(ws, out);   // step 5 -> d_out
}

// Round 2
// 338.896 us; speedup vs baseline: 1.4761x; 1.4761x over previous
//
#include <hip/hip_runtime.h>

// ExpFlow: scaling-and-squaring exponentiation of a velocity field.
// x: [N=2, C=3, D=128, H=128, W=128] f32. u0 = x/32; 5x: u <- u + warp(u, id+u).
// SoA layout [N,3,D,H,W] end-to-end; ping-pong d_ws <-> d_out (5th step -> d_out).
//
// R2: border-clamp folded into (x0,wx) so corners form a true 2x2x2 cube ->
// x-pair gathers as float2 (12 instead of 24 loads); 2 voxels per thread so
// base loads/stores are float2. Memory instrs per voxel: 30 -> ~15/2voxel+12.

namespace {
constexpr int kD = 128, kH = 128, kW = 128, kN = 2, kC = 3;
constexpr int kPlane = kD * kH * kW;        // 2^21
constexpr int kVol   = kC * kPlane;
constexpr int kTotalVox   = kN * kPlane;
constexpr int kTotalElems = kN * kVol;      // 12,582,912
constexpr float kScale0 = 1.0f / 32.0f;
}

typedef float f32x2 __attribute__((ext_vector_type(2)));
typedef float f32x4 __attribute__((ext_vector_type(4)));

__global__ __launch_bounds__(256) void scale_kernel(const float* __restrict__ x,
                                                    float* __restrict__ u) {
    int i = blockIdx.x * 256 + threadIdx.x;
    f32x4 v = *(const f32x4*)(x + 4 * i);
    v *= kScale0;
    *(f32x4*)(u + 4 * i) = v;
}

__global__ __launch_bounds__(256) void step_kernel(const float* __restrict__ u,
                                                   float* __restrict__ out) {
    int tid = blockIdx.x * 256 + threadIdx.x;       // < kTotalVox/2
    int n  = tid >> 20;                              // kPlane/2 = 2^20 per batch
    int rr = (tid & ((kPlane / 2) - 1)) << 1;        // even voxel index in plane
    int w = rr & 127;
    int h = (rr >> 7) & 127;
    int d = rr >> 14;

    const float* __restrict__ ub = u + n * kVol;

    // Base velocity for the two voxels (w, w+1), per channel. 8B-aligned.
    f32x2 bx = *(const f32x2*)(ub + rr);
    f32x2 by = *(const f32x2*)(ub + kPlane + rr);
    f32x2 bz = *(const f32x2*)(ub + 2 * kPlane + rr);

    float res[3][2];

    #pragma unroll
    for (int j = 0; j < 2; ++j) {
        float px = fminf(fmaxf((float)(w + j) + bx[j] * 63.5f, 0.0f), 127.0f);
        float py = fminf(fmaxf((float)h       + by[j] * 63.5f, 0.0f), 127.0f);
        float pz = fminf(fmaxf((float)d       + bz[j] * 63.5f, 0.0f), 127.0f);

        // Fold border clamp into the low corner: x0<=126 so x1=x0+1 always.
        // At px==127: x0'=126, wx'=1 -> selects v127 (same as wx=0 with both
        // corners at 127). Interior unchanged.
        int x0 = min((int)floorf(px), 126);
        int y0 = min((int)floorf(py), 126);
        int z0 = min((int)floorf(pz), 126);
        float wx = px - (float)x0, wy = py - (float)y0, wz = pz - (float)z0;
        float omx = 1.0f - wx, omy = 1.0f - wy, omz = 1.0f - wz;

        int o = (z0 << 14) + (y0 << 7) + x0;     // (z0,y0) row, x0 column
        // rows: o (z0,y0), o+128 (z0,y1), o+16384 (z1,y0), o+16512 (z1,y1)

        #pragma unroll
        for (int c = 0; c < 3; ++c) {
            const float* __restrict__ up = ub + c * kPlane;
            f32x2 v00 = *(const f32x2*)(up + o);
            f32x2 v01 = *(const f32x2*)(up + o + 128);
            f32x2 v10 = *(const f32x2*)(up + o + 16384);
            f32x2 v11 = *(const f32x2*)(up + o + 16512);
            // lerp x, then y, then z (matches reference ordering)
            float c00 = v00.x * omx + v00.y * wx;
            float c01 = v01.x * omx + v01.y * wx;
            float c10 = v10.x * omx + v10.y * wx;
            float c11 = v11.x * omx + v11.y * wx;
            float c0 = c00 * omy + c01 * wy;
            float c1 = c10 * omy + c11 * wy;
            float s  = c0 * omz + c1 * wz;
            float base = (c == 0) ? bx[j] : (c == 1) ? by[j] : bz[j];
            res[c][j] = base + s;
        }
    }

    float* __restrict__ ob = out + n * kVol;
    *(f32x2*)(ob + rr)              = f32x2{res[0][0], res[0][1]};
    *(f32x2*)(ob + kPlane + rr)     = f32x2{res[1][0], res[1][1]};
    *(f32x2*)(ob + 2 * kPlane + rr) = f32x2{res[2][0], res[2][1]};
}

extern "C" void kernel_launch(void* const* d_in, const int* in_sizes, int n_in,
                              void* d_out, int out_size, void* d_ws, size_t ws_size,
                              hipStream_t stream) {
    const float* x = (const float*)d_in[0];
    float* out = (float*)d_out;
    float* ws  = (float*)d_ws;

    scale_kernel<<<kTotalElems / (256 * 4), 256, 0, stream>>>(x, ws);

    const int grd = kTotalVox / (256 * 2);
    step_kernel<<<grd, 256, 0, stream>>>(ws, out);   // step 1
    step_kernel<<<grd, 256, 0, stream>>>(out, ws);   // step 2
    step_kernel<<<grd, 256, 0, stream>>>(ws, out);   // step 3
    step_kernel<<<grd, 256, 0, stream>>>(out, ws);   // step 4
    step_kernel<<<grd, 256, 0, stream>>>(ws, out);   // step 5 -> d_out
}

// Round 3
// 333.038 us; speedup vs baseline: 1.5021x; 1.0176x over previous
//
#include <hip/hip_runtime.h>

// ExpFlow: scaling-and-squaring exponentiation of a velocity field.
// x: [N=2, C=3, D=128, H=128, W=128] f32. u0 = x/32; 5x: u <- u + warp(u, id+u).
// SoA layout [N,3,D,H,W]; chain s1:x->out(fused scale), s2:out->ws, s3:ws->out,
// s4:out->ws, s5:ws->out.
//
// R3: all 24 gather loads issued up-front into an explicit register array
// (raises MLP per wave; R2's VGPR=40 showed the compiler was serializing
// loads), scale pass fused into step 1.

namespace {
constexpr int kD = 128, kH = 128, kW = 128, kN = 2, kC = 3;
constexpr int kPlane = kD * kH * kW;        // 2^21
constexpr int kVol   = kC * kPlane;
constexpr int kTotalVox = kN * kPlane;
constexpr float kScale0 = 1.0f / 32.0f;
}

typedef float f32x2 __attribute__((ext_vector_type(2)));

template <bool SCALED>
__global__ __launch_bounds__(256) void step_kernel(const float* __restrict__ u,
                                                   float* __restrict__ out) {
    int tid = blockIdx.x * 256 + threadIdx.x;       // < kTotalVox/2
    int n  = tid >> 20;                              // kPlane/2 = 2^20 per batch
    int rr = (tid & ((kPlane / 2) - 1)) << 1;        // even voxel index in plane
    int w = rr & 127;
    int h = (rr >> 7) & 127;
    int d = rr >> 14;

    const float* __restrict__ ub = u + n * kVol;

    // Base velocity for voxels (w, w+1), per channel.
    f32x2 bx = *(const f32x2*)(ub + rr);
    f32x2 by = *(const f32x2*)(ub + kPlane + rr);
    f32x2 bz = *(const f32x2*)(ub + 2 * kPlane + rr);
    if (SCALED) { bx *= kScale0; by *= kScale0; bz *= kScale0; }

    // Phase 1: compute both voxels' cube offsets + lerp weights.
    int   o[2];
    float wxa[2], wya[2], wza[2];
    #pragma unroll
    for (int j = 0; j < 2; ++j) {
        float px = fminf(fmaxf((float)(w + j) + bx[j] * 63.5f, 0.0f), 127.0f);
        float py = fminf(fmaxf((float)h       + by[j] * 63.5f, 0.0f), 127.0f);
        float pz = fminf(fmaxf((float)d       + bz[j] * 63.5f, 0.0f), 127.0f);
        // Fold border clamp into low corner (x0<=126, wx in [0,1]).
        int x0 = min((int)floorf(px), 126);
        int y0 = min((int)floorf(py), 126);
        int z0 = min((int)floorf(pz), 126);
        wxa[j] = px - (float)x0;
        wya[j] = py - (float)y0;
        wza[j] = pz - (float)z0;
        o[j] = (z0 << 14) + (y0 << 7) + x0;
    }

    // Phase 2: issue ALL 24 float2 gathers before any consumption.
    // rows: +0 (z0,y0), +128 (z0,y1), +16384 (z1,y0), +16512 (z1,y1)
    f32x2 g[3][4][2];
    #pragma unroll
    for (int c = 0; c < 3; ++c) {
        const float* __restrict__ up = ub + c * kPlane;
        #pragma unroll
        for (int j = 0; j < 2; ++j) {
            g[c][0][j] = *(const f32x2*)(up + o[j]);
            g[c][1][j] = *(const f32x2*)(up + o[j] + 128);
            g[c][2][j] = *(const f32x2*)(up + o[j] + 16384);
            g[c][3][j] = *(const f32x2*)(up + o[j] + 16512);
        }
    }

    // Phase 3: arithmetic (lerp x, then y, then z — reference ordering).
    float res[3][2];
    #pragma unroll
    for (int j = 0; j < 2; ++j) {
        float wx = wxa[j], wy = wya[j], wz = wza[j];
        float omx = 1.0f - wx, omy = 1.0f - wy, omz = 1.0f - wz;
        #pragma unroll
        for (int c = 0; c < 3; ++c) {
            f32x2 v00 = g[c][0][j], v01 = g[c][1][j];
            f32x2 v10 = g[c][2][j], v11 = g[c][3][j];
            if (SCALED) { v00 *= kScale0; v01 *= kScale0; v10 *= kScale0; v11 *= kScale0; }
            float c00 = v00.x * omx + v00.y * wx;
            float c01 = v01.x * omx + v01.y * wx;
            float c10 = v10.x * omx + v10.y * wx;
            float c11 = v11.x * omx + v11.y * wx;
            float c0 = c00 * omy + c01 * wy;
            float c1 = c10 * omy + c11 * wy;
            float s  = c0 * omz + c1 * wz;
            float base = (c == 0) ? bx[j] : (c == 1) ? by[j] : bz[j];
            res[c][j] = base + s;
        }
    }

    float* __restrict__ ob = out + n * kVol;
    *(f32x2*)(ob + rr)              = f32x2{res[0][0], res[0][1]};
    *(f32x2*)(ob + kPlane + rr)     = f32x2{res[1][0], res[1][1]};
    *(f32x2*)(ob + 2 * kPlane + rr) = f32x2{res[2][0], res[2][1]};
}

extern "C" void kernel_launch(void* const* d_in, const int* in_sizes, int n_in,
                              void* d_out, int out_size, void* d_ws, size_t ws_size,
                              hipStream_t stream) {
    const float* x = (const float*)d_in[0];
    float* out = (float*)d_out;
    float* ws  = (float*)d_ws;

    const int grd = kTotalVox / (256 * 2);
    step_kernel<true ><<<grd, 256, 0, stream>>>(x,   out);  // step 1 (scale fused)
    step_kernel<false><<<grd, 256, 0, stream>>>(out, ws);   // step 2
    step_kernel<false><<<grd, 256, 0, stream>>>(ws,  out);  // step 3
    step_kernel<false><<<grd, 256, 0, stream>>>(out, ws);   // step 4
    step_kernel<false><<<grd, 256, 0, stream>>>(ws,  out);  // step 5 -> d_out
}